// Round 1
// baseline (117.950 us; speedup 1.0000x reference)
//
#include <hip/hip_runtime.h>

// Retention EMA: xi_t = 0.5*xi_{t-1} + 0.5*sigmoid(x_t), xi_0 = 0, over axis N
// of x[B=8, N=4096, D=2048] (f32). Constant decay 0.5 => influence horizon is
// ~32 steps (0.5^32 ~ 2.3e-10 absolute). So we split N into independent chunks
// of NCHUNK steps; each chunk warms its state from zero over a HALO=32 step
// prefix read. No cross-block communication, pure streaming, memory-bound.

#define N_SEQ   4096
#define D_DIM   2048
#define NCHUNK  256
#define HALO    32
#define TPB     256
#define VEC     2      // float2 per thread: 8 B/lane coalesced loads/stores

__global__ __launch_bounds__(TPB) void retention_kernel(
    const float* __restrict__ x, float* __restrict__ out)
{
    // grid: (D/(TPB*VEC), N/NCHUNK, B) = (4, 16, 8)
    const int dg = blockIdx.x;
    const int nc = blockIdx.y;
    const int b  = blockIdx.z;

    const int d0     = dg * (TPB * VEC) + (int)threadIdx.x * VEC;
    const int nstart = nc * NCHUNK;
    const int nwarm  = (nc == 0) ? 0 : HALO;   // chunk 0 starts exactly at xi=0

    const size_t stride2 = D_DIM / 2;          // row stride in float2 units

    const float2* __restrict__ xp = reinterpret_cast<const float2*>(
        x + ((size_t)b * N_SEQ + (size_t)(nstart - nwarm)) * D_DIM + d0);
    float2* __restrict__ op = reinterpret_cast<float2*>(
        out + ((size_t)b * N_SEQ + (size_t)nstart) * D_DIM + d0);

    float xi0 = 0.0f, xi1 = 0.0f;

    // Halo warm-up: loads only, no stores.
    for (int n = 0; n < nwarm; ++n) {
        float2 v = xp[(size_t)n * stride2];
        xi0 = 0.5f * (xi0 + 1.0f / (1.0f + __expf(-v.x)));
        xi1 = 0.5f * (xi1 + 1.0f / (1.0f + __expf(-v.y)));
    }
    xp += (size_t)nwarm * stride2;

    // Main chunk: 256 steps, store every step.
    #pragma unroll 8
    for (int n = 0; n < NCHUNK; ++n) {
        float2 v = xp[(size_t)n * stride2];
        xi0 = 0.5f * (xi0 + 1.0f / (1.0f + __expf(-v.x)));
        xi1 = 0.5f * (xi1 + 1.0f / (1.0f + __expf(-v.y)));
        float2 o;
        o.x = xi0;
        o.y = xi1;
        op[(size_t)n * stride2] = o;
    }
}

extern "C" void kernel_launch(void* const* d_in, const int* in_sizes, int n_in,
                              void* d_out, int out_size, void* d_ws, size_t ws_size,
                              hipStream_t stream)
{
    const float* x = (const float*)d_in[0];
    float* out     = (float*)d_out;

    const int B = in_sizes[0] / (N_SEQ * D_DIM);   // = 8

    dim3 grid(D_DIM / (TPB * VEC), N_SEQ / NCHUNK, B);
    dim3 block(TPB);
    retention_kernel<<<grid, block, 0, stream>>>(x, out);
}

// Round 2
// 86.388 us; speedup vs baseline: 1.3653x; 1.3653x over previous
//
#include <hip/hip_runtime.h>

// Retention EMA: xi_t = 0.5*xi_{t-1} + 0.5*sigmoid(x_t), xi_0 = 0, over axis N
// of x[B=8, N=4096, D=2048] (f32). Constant decay 0.5 => influence horizon
// ~32 steps (0.5^32 ~ 2.3e-10). N is split into independent 256-step chunks,
// each warmed up from zero over a 32-step halo. Pure streaming, memory-bound.
//
// Round-2 changes vs round-1 (118 us, 4.8 TB/s effective):
//  - sigmoid via raw v_rcp_f32 (__builtin_amdgcn_rcpf) instead of IEEE div
//    (~10-instr div_scale/div_fmas/div_fixup sequence on the serial chain).
//  - VEC 2 -> 1: grid 512 -> 1024 blocks = 16 waves/CU (was 8) for better
//    latency hiding. 4 B/lane is still fully coalesced (256 B per wave-load).
//  - nontemporal stores: write stream is never re-read; keep it out of L2/L3
//    (input alone ~= L3 capacity).

#define N_SEQ   4096
#define D_DIM   2048
#define NCHUNK  256
#define HALO    32
#define TPB     256

__device__ __forceinline__ float half_sigmoid(float v) {
    // 0.5 * sigmoid(v) folded into the EMA update below; here: sigmoid(v)
    return __builtin_amdgcn_rcpf(1.0f + __expf(-v));
}

__global__ __launch_bounds__(TPB) void retention_kernel(
    const float* __restrict__ x, float* __restrict__ out)
{
    // grid: (D/TPB, N/NCHUNK, B) = (8, 16, 8) = 1024 blocks
    const int dg = blockIdx.x;
    const int nc = blockIdx.y;
    const int b  = blockIdx.z;

    const int d0     = dg * TPB + (int)threadIdx.x;
    const int nstart = nc * NCHUNK;

    const float* __restrict__ xp =
        x + ((size_t)b * N_SEQ + (size_t)nstart) * D_DIM + d0;
    float* __restrict__ op =
        out + ((size_t)b * N_SEQ + (size_t)nstart) * D_DIM + d0;

    float xi = 0.0f;

    if (nc != 0) {
        // Halo warm-up: loads only, no stores. Fixed 32 iterations.
        const float* __restrict__ hp = xp - (size_t)HALO * D_DIM;
        #pragma unroll
        for (int n = 0; n < HALO; ++n) {
            float v = hp[(size_t)n * D_DIM];
            xi = 0.5f * (xi + half_sigmoid(v));
        }
    }

    // Main chunk: 256 steps, store every step.
    #pragma unroll 8
    for (int n = 0; n < NCHUNK; ++n) {
        float v = xp[(size_t)n * D_DIM];
        xi = 0.5f * (xi + half_sigmoid(v));
        __builtin_nontemporal_store(xi, &op[(size_t)n * D_DIM]);
    }
}

extern "C" void kernel_launch(void* const* d_in, const int* in_sizes, int n_in,
                              void* d_out, int out_size, void* d_ws, size_t ws_size,
                              hipStream_t stream)
{
    const float* x = (const float*)d_in[0];
    float* out     = (float*)d_out;

    const int B = in_sizes[0] / (N_SEQ * D_DIM);   // = 8

    dim3 grid(D_DIM / TPB, N_SEQ / NCHUNK, B);
    dim3 block(TPB);
    retention_kernel<<<grid, block, 0, stream>>>(x, out);
}

// Round 3
// 83.917 us; speedup vs baseline: 1.4056x; 1.0294x over previous
//
#include <hip/hip_runtime.h>

// Retention EMA: xi_t = 0.5*xi_{t-1} + 0.5*sigmoid(x_t), xi_0 = 0, over axis N
// of x[B=8, N=4096, D=2048] (f32). Constant decay 0.5 => influence horizon is
// tiny: truncating history at H steps adds <= 0.5*0.5^H absolute error
// (state bounded by 0.5). H=16 -> 7.6e-6, invisible vs the 1.85e-2 threshold.
// N is split into independent 256-step chunks, each warmed up from zero over
// a 16-step halo. Pure streaming, memory-bound.
//
// Round-3 change vs round-2 (86.4 us, 6.58 TB/s incl. halo):
//  - HALO 32 -> 16: halo re-read overhead 12.5% -> 5.86% of input bytes.
//    Traffic 568 -> 552.5 MB. Everything else (rcp-sigmoid, VEC=1 coalesced
//    columns, 1024-block grid = 16 waves/CU, nontemporal stores) unchanged —
//    round 2 showed that configuration runs at/above the copy ceiling.

#define N_SEQ   4096
#define D_DIM   2048
#define NCHUNK  256
#define HALO    16
#define TPB     256

__device__ __forceinline__ float sigmoid_fast(float v) {
    return __builtin_amdgcn_rcpf(1.0f + __expf(-v));   // raw v_rcp_f32, ~1 ulp
}

__global__ __launch_bounds__(TPB) void retention_kernel(
    const float* __restrict__ x, float* __restrict__ out)
{
    // grid: (D/TPB, N/NCHUNK, B) = (8, 16, 8) = 1024 blocks, 16 waves/CU
    const int dg = blockIdx.x;
    const int nc = blockIdx.y;
    const int b  = blockIdx.z;

    const int d0     = dg * TPB + (int)threadIdx.x;
    const int nstart = nc * NCHUNK;

    const float* __restrict__ xp =
        x + ((size_t)b * N_SEQ + (size_t)nstart) * D_DIM + d0;
    float* __restrict__ op =
        out + ((size_t)b * N_SEQ + (size_t)nstart) * D_DIM + d0;

    float xi = 0.0f;

    if (nc != 0) {
        // Halo warm-up: loads only, no stores. Fixed 16 iterations.
        const float* __restrict__ hp = xp - (size_t)HALO * D_DIM;
        #pragma unroll
        for (int n = 0; n < HALO; ++n) {
            float v = hp[(size_t)n * D_DIM];
            xi = 0.5f * (xi + sigmoid_fast(v));
        }
    }

    // Main chunk: 256 steps, store every step.
    #pragma unroll 8
    for (int n = 0; n < NCHUNK; ++n) {
        float v = xp[(size_t)n * D_DIM];
        xi = 0.5f * (xi + sigmoid_fast(v));
        __builtin_nontemporal_store(xi, &op[(size_t)n * D_DIM]);
    }
}

extern "C" void kernel_launch(void* const* d_in, const int* in_sizes, int n_in,
                              void* d_out, int out_size, void* d_ws, size_t ws_size,
                              hipStream_t stream)
{
    const float* x = (const float*)d_in[0];
    float* out     = (float*)d_out;

    const int B = in_sizes[0] / (N_SEQ * D_DIM);   // = 8

    dim3 grid(D_DIM / TPB, N_SEQ / NCHUNK, B);
    dim3 block(TPB);
    retention_kernel<<<grid, block, 0, stream>>>(x, out);
}